// Round 8
// baseline (781.271 us; speedup 1.0000x reference)
//
#include <hip/hip_runtime.h>
#include <cstdint>
#include <cstddef>

typedef unsigned short u16;
typedef unsigned int u32;

typedef unsigned short u16x8 __attribute__((ext_vector_type(8)));
typedef __bf16 bf16x8 __attribute__((ext_vector_type(8)));
typedef float f32x4 __attribute__((ext_vector_type(4)));
typedef float f32x8 __attribute__((ext_vector_type(8)));

#define NB   128
#define NL   192
#define NTOK (NB * NL)   // 24576
#define DIM  512
#define HID  2048
#define LDSS 40          // padded LDS row stride (u16): 80 B, 16B-aligned rows

static __device__ __forceinline__ float bf2f(u16 h) {
    union { u32 u; float f; } v; v.u = ((u32)h) << 16; return v.f;
}
static __device__ __forceinline__ u16 f2bf(float f) {
    union { float f; u32 u; } v; v.f = f;
    u32 u = v.u + 0x7FFF + ((v.u >> 16) & 1);  // RNE
    return (u16)(u >> 16);
}

// -------- weight transpose + cast: in f32 (K,N) -> out bf16 (N,K) --------
__global__ void transpose_f2b(const float* __restrict__ in, u16* __restrict__ out,
                              int K, int N) {
    __shared__ float tile[32][33];
    int tx = threadIdx.x & 31, ty = threadIdx.x >> 5;  // 32 x 8
    int n0 = blockIdx.x * 32, k0 = blockIdx.y * 32;
#pragma unroll
    for (int i = 0; i < 4; i++)
        tile[ty + i * 8][tx] = in[(size_t)(k0 + ty + i * 8) * N + n0 + tx];
    __syncthreads();
#pragma unroll
    for (int i = 0; i < 4; i++)
        out[(size_t)(n0 + ty + i * 8) * K + k0 + tx] = f2bf(tile[tx][ty + i * 8]);
}

// -------- embedding: emb[t=l*B+b][d] = sum of 5 f32 tables; f32 + bf16 out ----
static __device__ __forceinline__ void add8f(float* acc, const float* p) {
    f32x8 v = *(const f32x8*)p;
#pragma unroll
    for (int i = 0; i < 8; i++) acc[i] += v[i];
}

__global__ void embed_kernel(const int* __restrict__ element, const int* __restrict__ aroma,
                             const int* __restrict__ charge, const int* __restrict__ segment,
                             const float* __restrict__ pe, const float* __restrict__ E_elem,
                             const float* __restrict__ E_charge, const float* __restrict__ E_aroma,
                             const float* __restrict__ E_seg,
                             float* __restrict__ emb32, u16* __restrict__ emb16) {
    int t = blockIdx.x * 4 + (threadIdx.x >> 6);  // one wave per token
    int lane = threadIdx.x & 63;
    int l = t >> 7, b = t & 127;                  // t = l*128 + b
    int d = lane * 8;
    int idx = b * NL + l;
    int e = element[idx];
    int a = aroma[idx];
    int c = charge[idx] + 6;
    int s = segment[idx];
    float acc[8] = {0, 0, 0, 0, 0, 0, 0, 0};
    add8f(acc, E_elem  + (size_t)e * DIM + d);
    add8f(acc, pe      + (size_t)l * DIM + d);
    add8f(acc, E_aroma + (size_t)a * DIM + d);
    add8f(acc, E_charge+ (size_t)c * DIM + d);
    add8f(acc, E_seg   + (size_t)s * DIM + d);
    f32x8 o32; u16x8 o16;
#pragma unroll
    for (int i = 0; i < 8; i++) { o32[i] = acc[i]; o16[i] = f2bf(acc[i]); }
    *(f32x8*)(emb32 + (size_t)t * DIM + d) = o32;
    *(u16x8*)(emb16 + (size_t)t * DIM + d) = o16;
}

// -------- GEMM: C[M,N] = A[M,K] @ BT[N,K]^T (+f32 bias, relu, bf16/f32 resid) --
// 128x256 block tile, 4 waves, wave tile 64x128 (4x8 frags, acc in AGPR).
// Staging = AITER-style: buffer_load -> VGPR prefetch (distance 1) ->
// ds_write_b128 (padded stride 40), ONE raw barrier per iter
// (s_waitcnt lgkmcnt(0); s_barrier) — prefetch global loads stay in flight
// across the barrier; the compiler inserts the precise vmcnt before the
// dependent ds_write of the next iteration. No global_load_lds: R6 counters
// showed the LDS-DMA path capped effective HBM at ~1.3 TB/s.
// 2-buffer LDS ping-pong is safe with one barrier/iter: buf X's reads (iter
// k-1) and next writes (iter k+1) are separated by the barrier in iter k.
// Requires M%128==0, N%256==0, K%32==0.
__global__ __launch_bounds__(256) void gemm_bt(
    const u16* __restrict__ A, const u16* __restrict__ BT,
    const float* __restrict__ bias, const u16* __restrict__ resid16,
    const float* __restrict__ resid32,
    u16* __restrict__ C, int M, int N, int K, int do_relu) {
    __shared__ __align__(16) u16 As[2][128 * LDSS];   // 20 KB
    __shared__ __align__(16) u16 Bs[2][256 * LDSS];   // 40 KB

    const int tid  = threadIdx.x;
    const int wave = tid >> 6;
    const int lane = tid & 63;
    const int m0 = blockIdx.x * 128;
    const int n0 = blockIdx.y * 256;
    const int wm = (wave >> 1) * 64;    // wave's 64-row half (M)
    const int wn = (wave & 1) * 128;    // wave's 128-col half (N)
    const int lr = lane >> 2;           // staging: row within 16-row group
    const int lc = (lane & 3) * 8;      // staging: k-chunk (8 bf16 = 16 B)
    const int fr = lane & 15;           // fragment row/col
    const int fq = lane >> 4;           // fragment k-quad

    f32x4 acc[4][8] = {};

    // wave w stages A rows {w*16+lr, 64+w*16+lr}, B rows {w*16+lr +0,64,128,192}
    const u16* Ag0 = A  + (size_t)(m0 + wave * 16 + lr) * K + lc;
    const u16* Ag1 = Ag0 + (size_t)64 * K;
    const u16* Bg0 = BT + (size_t)(n0 + wave * 16 + lr) * K + lc;
    const u16* Bg1 = Bg0 + (size_t)64 * K;
    const u16* Bg2 = Bg0 + (size_t)128 * K;
    const u16* Bg3 = Bg0 + (size_t)192 * K;
    // LDS staging addresses (padded stride)
    u16* wA0 = &As[0][(wave * 16 + lr) * LDSS + lc];
    u16* wA1 = &As[0][(64 + wave * 16 + lr) * LDSS + lc];
    u16* wB0 = &Bs[0][(wave * 16 + lr) * LDSS + lc];
    u16* wB1 = &Bs[0][(64 + wave * 16 + lr) * LDSS + lc];
    u16* wB2 = &Bs[0][(128 + wave * 16 + lr) * LDSS + lc];
    u16* wB3 = &Bs[0][(192 + wave * 16 + lr) * LDSS + lc];
    const int bufOffA = 128 * LDSS;     // u16 elements between As[0] and As[1]
    const int bufOffB = 256 * LDSS;

    const int kIters = K >> 5;
    // prefetch tile 0
    u16x8 pa0 = *(const u16x8*)(Ag0);
    u16x8 pa1 = *(const u16x8*)(Ag1);
    u16x8 pb0 = *(const u16x8*)(Bg0);
    u16x8 pb1 = *(const u16x8*)(Bg1);
    u16x8 pb2 = *(const u16x8*)(Bg2);
    u16x8 pb3 = *(const u16x8*)(Bg3);

    for (int k = 0; k < kIters; ++k) {
        const int cur = k & 1;
        const int oA = cur * bufOffA, oB = cur * bufOffB;
        // stage tile k (compiler emits s_waitcnt vmcnt(...) before these)
        *(u16x8*)(wA0 + oA) = pa0;
        *(u16x8*)(wA1 + oA) = pa1;
        *(u16x8*)(wB0 + oB) = pb0;
        *(u16x8*)(wB1 + oB) = pb1;
        *(u16x8*)(wB2 + oB) = pb2;
        *(u16x8*)(wB3 + oB) = pb3;
        // issue prefetch of tile k+1 (stays in flight across the barrier)
        const int kn = (k + 1 < kIters) ? (k + 1) << 5 : 0;
        pa0 = *(const u16x8*)(Ag0 + kn);
        pa1 = *(const u16x8*)(Ag1 + kn);
        pb0 = *(const u16x8*)(Bg0 + kn);
        pb1 = *(const u16x8*)(Bg1 + kn);
        pb2 = *(const u16x8*)(Bg2 + kn);
        pb3 = *(const u16x8*)(Bg3 + kn);
        // LDS writes visible to all waves; do NOT drain vmcnt here.
        asm volatile("s_waitcnt lgkmcnt(0)\n\ts_barrier" ::: "memory");

        bf16x8 af[4];
#pragma unroll
        for (int i = 0; i < 4; i++)
            af[i] = *(const bf16x8*)(&As[cur][(wm + i * 16 + fr) * LDSS + fq * 8]);
#pragma unroll
        for (int j = 0; j < 8; j++) {
            bf16x8 bg = *(const bf16x8*)(&Bs[cur][(wn + j * 16 + fr) * LDSS + fq * 8]);
#pragma unroll
            for (int i = 0; i < 4; i++)
                acc[i][j] = __builtin_amdgcn_mfma_f32_16x16x32_bf16(
                    af[i], bg, acc[i][j], 0, 0, 0);
        }
    }

    // epilogue: C/D layout col = lane&15 (n), row = (lane>>4)*4 + reg (m)
#pragma unroll
    for (int j = 0; j < 8; j++) {
        int n = n0 + wn + j * 16 + fr;
        float bv = bias[n];
#pragma unroll
        for (int i = 0; i < 4; i++) {
#pragma unroll
            for (int r = 0; r < 4; r++) {
                int m = m0 + wm + i * 16 + fq * 4 + r;
                float v = acc[i][j][r] + bv;
                if (do_relu) v = fmaxf(v, 0.0f);
                if (resid16) v += bf2f(resid16[(size_t)m * N + n]);
                if (resid32) v += resid32[(size_t)m * N + n];
                C[(size_t)m * N + n] = f2bf(v);
            }
        }
    }
}

// -------- aggregation + final residual (in-place on d_out, f32) --------
// out[t=l*B+b][d] = emb32[t][d] + sum_m (bond[b,l,m]!=l) * msg[bond*B+b][d]
__global__ void agg_kernel(const float* __restrict__ emb32, const u16* __restrict__ msg,
                           const int* __restrict__ bond, float* __restrict__ out) {
    int t = blockIdx.x * 4 + (threadIdx.x >> 6);  // one wave per token
    int lane = threadIdx.x & 63;
    int l = t >> 7, b = t & 127;
    int d = lane * 8;
    float acc[8];
    {
        f32x8 v = *(const f32x8*)(emb32 + (size_t)t * DIM + d);
#pragma unroll
        for (int i = 0; i < 8; i++) acc[i] = v[i];
    }
    const int* bp = bond + ((size_t)b * NL + l) * 6;
#pragma unroll
    for (int m = 0; m < 6; m++) {
        int j = bp[m];
        if (j != l) {  // wave-uniform branch
            u16x8 g = *(const u16x8*)(msg + ((size_t)j * NB + b) * DIM + d);
#pragma unroll
            for (int i = 0; i < 8; i++) acc[i] += bf2f(g[i]);
        }
    }
    f32x8 o;
#pragma unroll
    for (int i = 0; i < 8; i++) o[i] = acc[i];
    *(f32x8*)(out + (size_t)t * DIM + d) = o;
}

extern "C" void kernel_launch(void* const* d_in, const int* in_sizes, int n_in,
                              void* d_out, int out_size, void* d_ws, size_t ws_size,
                              hipStream_t stream) {
    const int* element = (const int*)d_in[0];
    const int* bond    = (const int*)d_in[1];
    const int* aroma   = (const int*)d_in[2];
    const int* charge  = (const int*)d_in[3];
    const int* segment = (const int*)d_in[4];
    const float* pe      = (const float*)d_in[5];
    const float* E_elem  = (const float*)d_in[6];
    const float* E_charge= (const float*)d_in[7];
    const float* E_aroma = (const float*)d_in[8];
    const float* E_seg   = (const float*)d_in[9];
    const float* W1 = (const float*)d_in[10];
    const float* b1 = (const float*)d_in[11];
    const float* W2 = (const float*)d_in[12];
    const float* b2 = (const float*)d_in[13];
    const float* W3 = (const float*)d_in[14];
    const float* b3 = (const float*)d_in[15];
    const float* W4 = (const float*)d_in[16];
    const float* b4 = (const float*)d_in[17];
    const float* W5 = (const float*)d_in[18];
    const float* b5 = (const float*)d_in[19];

    // f32 emb lives in d_out (50 MiB); agg rewrites d_out in place at the end.
    float* emb32 = (float*)d_out;

    // dynamic ws layout — never exceed ws_size
    char* ws = (char*)d_ws;
    size_t woff = 0;
    auto take = [&](size_t bytes) -> u16* {
        u16* p = (u16*)(ws + woff);
        woff += (bytes + 255) & ~(size_t)255;
        return p;
    };
    u16* W1T = take((size_t)HID * DIM * 2);   // 2048x512 bf16
    u16* W2T = take((size_t)DIM * HID * 2);   // 512x2048
    u16* W3T = take((size_t)HID * DIM * 2);
    u16* W4T = take((size_t)DIM * HID * 2);
    u16* W5T = take((size_t)DIM * DIM * 2);
    u16* emb16 = take((size_t)NTOK * DIM * 2);  // 24 MiB
    u16* msg   = take((size_t)NTOK * DIM * 2);  // 24 MiB

    // pick largest M-chunk that fits (CM multiple of 128): h + xa + xb, bf16
    static const int ncs[] = {1, 2, 3, 4, 6, 8, 12, 16, 24, 32, 48, 64, 96, 192};
    int CM = 128;
    for (int nc : ncs) {
        int cm = NTOK / nc;
        if (cm % 128) continue;
        size_t need = woff + ((size_t)cm * HID * 2 + 256)
                           + ((size_t)cm * DIM * 2 + 256) * 2;
        if (need <= ws_size) { CM = cm; break; }
    }
    u16* hC  = take((size_t)CM * HID * 2);
    u16* xaC = take((size_t)CM * DIM * 2);
    u16* xbC = take((size_t)CM * DIM * 2);

    // weight transposes + cast: f32 (K,N) -> bf16 (N,K)
    transpose_f2b<<<dim3(HID / 32, DIM / 32), 256, 0, stream>>>(W1, W1T, DIM, HID);
    transpose_f2b<<<dim3(DIM / 32, HID / 32), 256, 0, stream>>>(W2, W2T, HID, DIM);
    transpose_f2b<<<dim3(HID / 32, DIM / 32), 256, 0, stream>>>(W3, W3T, DIM, HID);
    transpose_f2b<<<dim3(DIM / 32, HID / 32), 256, 0, stream>>>(W4, W4T, HID, DIM);
    transpose_f2b<<<dim3(DIM / 32, DIM / 32), 256, 0, stream>>>(W5, W5T, DIM, DIM);

    embed_kernel<<<NTOK / 4, 256, 0, stream>>>(element, aroma, charge, segment, pe,
                                               E_elem, E_charge, E_aroma, E_seg,
                                               emb32, emb16);

    // MLP per M-chunk: x += relu(x@W1+b1)@W2+b2 ; x += relu(x@W3+b3)@W4+b4 ; msg = x@W5+b5
    for (int c0 = 0; c0 < NTOK; c0 += CM) {
        const u16* x16 = emb16 + (size_t)c0 * DIM;
        const float* x32 = emb32 + (size_t)c0 * DIM;
        u16* msgC = msg + (size_t)c0 * DIM;
        gemm_bt<<<dim3(CM / 128, HID / 256), 256, 0, stream>>>(x16, W1T, b1, nullptr, nullptr, hC,  CM, HID, DIM, 1);
        gemm_bt<<<dim3(CM / 128, DIM / 256), 256, 0, stream>>>(hC,  W2T, b2, nullptr, x32,     xaC, CM, DIM, HID, 0);
        gemm_bt<<<dim3(CM / 128, HID / 256), 256, 0, stream>>>(xaC, W3T, b3, nullptr, nullptr, hC,  CM, HID, DIM, 1);
        gemm_bt<<<dim3(CM / 128, DIM / 256), 256, 0, stream>>>(hC,  W4T, b4, xaC,    nullptr,  xbC, CM, DIM, HID, 0);
        gemm_bt<<<dim3(CM / 128, DIM / 256), 256, 0, stream>>>(xbC, W5T, b5, nullptr, nullptr, msgC, CM, DIM, DIM, 0);
    }

    agg_kernel<<<NTOK / 4, 256, 0, stream>>>(emb32, msg, bond, (float*)d_out);
}

// Round 9
// 697.903 us; speedup vs baseline: 1.1195x; 1.1195x over previous
//
#include <hip/hip_runtime.h>
#include <cstdint>
#include <cstddef>

typedef unsigned short u16;
typedef unsigned int u32;

typedef unsigned short u16x8 __attribute__((ext_vector_type(8)));
typedef __bf16 bf16x8 __attribute__((ext_vector_type(8)));
typedef float f32x4 __attribute__((ext_vector_type(4)));
typedef float f32x8 __attribute__((ext_vector_type(8)));

#define NB   128
#define NL   192
#define NTOK (NB * NL)   // 24576
#define DIM  512
#define HID  2048

static __device__ __forceinline__ float bf2f(u16 h) {
    union { u32 u; float f; } v; v.u = ((u32)h) << 16; return v.f;
}
static __device__ __forceinline__ u16 f2bf(float f) {
    union { float f; u32 u; } v; v.f = f;
    u32 u = v.u + 0x7FFF + ((v.u >> 16) & 1);  // RNE
    return (u16)(u >> 16);
}

// -------- weight transpose + cast: in f32 (K,N) -> out bf16 (N,K) --------
__global__ void transpose_f2b(const float* __restrict__ in, u16* __restrict__ out,
                              int K, int N) {
    __shared__ float tile[32][33];
    int tx = threadIdx.x & 31, ty = threadIdx.x >> 5;  // 32 x 8
    int n0 = blockIdx.x * 32, k0 = blockIdx.y * 32;
#pragma unroll
    for (int i = 0; i < 4; i++)
        tile[ty + i * 8][tx] = in[(size_t)(k0 + ty + i * 8) * N + n0 + tx];
    __syncthreads();
#pragma unroll
    for (int i = 0; i < 4; i++)
        out[(size_t)(n0 + ty + i * 8) * K + k0 + tx] = f2bf(tile[tx][ty + i * 8]);
}

// -------- embedding: emb[t=l*B+b][d] = sum of 5 f32 tables; f32 + bf16 out ----
static __device__ __forceinline__ void add8f(float* acc, const float* p) {
    f32x8 v = *(const f32x8*)p;
#pragma unroll
    for (int i = 0; i < 8; i++) acc[i] += v[i];
}

__global__ void embed_kernel(const int* __restrict__ element, const int* __restrict__ aroma,
                             const int* __restrict__ charge, const int* __restrict__ segment,
                             const float* __restrict__ pe, const float* __restrict__ E_elem,
                             const float* __restrict__ E_charge, const float* __restrict__ E_aroma,
                             const float* __restrict__ E_seg,
                             float* __restrict__ emb32, u16* __restrict__ emb16) {
    int t = blockIdx.x * 4 + (threadIdx.x >> 6);  // one wave per token
    int lane = threadIdx.x & 63;
    int l = t >> 7, b = t & 127;                  // t = l*128 + b
    int d = lane * 8;
    int idx = b * NL + l;
    int e = element[idx];
    int a = aroma[idx];
    int c = charge[idx] + 6;
    int s = segment[idx];
    float acc[8] = {0, 0, 0, 0, 0, 0, 0, 0};
    add8f(acc, E_elem  + (size_t)e * DIM + d);
    add8f(acc, pe      + (size_t)l * DIM + d);
    add8f(acc, E_aroma + (size_t)a * DIM + d);
    add8f(acc, E_charge+ (size_t)c * DIM + d);
    add8f(acc, E_seg   + (size_t)s * DIM + d);
    f32x8 o32; u16x8 o16;
#pragma unroll
    for (int i = 0; i < 8; i++) { o32[i] = acc[i]; o16[i] = f2bf(acc[i]); }
    *(f32x8*)(emb32 + (size_t)t * DIM + d) = o32;
    *(u16x8*)(emb16 + (size_t)t * DIM + d) = o16;
}

// -------- GEMM: C[M,N] = A[M,K] @ BT[N,K]^T (+f32 bias, relu, bf16/f32 resid) --
// Templated on WNF (wave N-frags): block tile 128 x (32*WNF), 4 waves, wave
// tile 64 x (16*WNF). WNF=8 -> 128x256 (N=2048 GEMMs), WNF=4 -> 128x128
// (N=512 GEMMs, grid 768 = 3/CU instead of 384 = 1.5/CU).
// Staging: global_load_lds width=16, 2-deep ping-pong (48/32 KB LDS -> 3-4
// blocks/CU = 12-16 waves/CU; R6's 3-deep 73 KB allowed only 2 blocks/CU and
// per-CU staged delivery stalled at ~8.5 B/cyc). Wait only own tile-k loads
// (vmcnt(2+WNF/2)) + raw s_barrier; tile k+1 stays in flight across it.
// Grid is (N-tiles, M-tiles): n fastest, so the n-group blocks sharing an
// A-tile run back-to-back (A fetched ~once; B L2-resident).
template <int WNF>
__global__ __launch_bounds__(256) void gemm_bt(
    const u16* __restrict__ A, const u16* __restrict__ BT,
    const float* __restrict__ bias, const u16* __restrict__ resid16,
    const float* __restrict__ resid32,
    u16* __restrict__ C, int M, int N, int K, int do_relu) {
    constexpr int NT = 32 * WNF;            // block N-tile
    constexpr int NGRP = NT / 64;           // B staging groups (64 rows each)
    constexpr int LCNT = 2 + NGRP;          // loads per wave per tile
    __shared__ __align__(16) u16 As[2][128 * 32];
    __shared__ __align__(16) u16 Bs[2][NT * 32];

    const int tid  = threadIdx.x;
    const int wave = tid >> 6;
    const int lane = tid & 63;
    const int m0 = blockIdx.y * 128;
    const int n0 = blockIdx.x * NT;
    const int wm = (wave >> 1) * 64;        // wave's 64-row half (M)
    const int wn = (wave & 1) * (16 * WNF); // wave's N half
    const int lr = lane >> 2;               // staging: row within 16-row group
    const int lc = (lane & 3) * 8;          // staging: k-chunk (16 B)
    const int fr = lane & 15;               // fragment row/col
    const int fq = lane >> 4;               // fragment k-quad

    f32x4 acc[4][WNF] = {};

    const u16* Ag0 = A  + (size_t)(m0 + wave * 16 + lr) * K + lc;
    const u16* Ag1 = Ag0 + (size_t)64 * K;
    const u16* Bg[NGRP];
#pragma unroll
    for (int g = 0; g < NGRP; g++)
        Bg[g] = BT + (size_t)(n0 + g * 64 + wave * 16 + lr) * K + lc;
    const int sA0 = (wave * 16) * 32;       // wave-uniform LDS offsets (u16)
    const int sA1 = (64 + wave * 16) * 32;
    int sB[NGRP];
#pragma unroll
    for (int g = 0; g < NGRP; g++) sB[g] = (g * 64 + wave * 16) * 32;

#define GLL(gp, lp) __builtin_amdgcn_global_load_lds(                            \
        (const __attribute__((address_space(1))) void*)(gp),                     \
        (__attribute__((address_space(3))) void*)(lp), 16, 0, 0)

    auto stage = [&](int buf, int k0) {
        GLL(Ag0 + k0, &As[buf][sA0]);
        GLL(Ag1 + k0, &As[buf][sA1]);
#pragma unroll
        for (int g = 0; g < NGRP; g++)
            GLL(Bg[g] + k0, &Bs[buf][sB[g]]);
    };

    const int kIters = K >> 5;
    stage(0, 0);          // LCNT loads in flight
    stage(1, 32);         // 2*LCNT

    for (int k = 0; k < kIters; ++k) {
        const int cur = k & 1;
        // wait own LCNT oldest loads (tile k); tile k+1 stays in flight.
        if constexpr (WNF == 8)
            asm volatile("s_waitcnt vmcnt(6)\n\ts_barrier" ::: "memory");
        else
            asm volatile("s_waitcnt vmcnt(4)\n\ts_barrier" ::: "memory");

        bf16x8 af[4];
#pragma unroll
        for (int i = 0; i < 4; i++)
            af[i] = *(const bf16x8*)(&As[cur][(wm + i * 16 + fr) * 32 + fq * 8]);
#pragma unroll
        for (int j = 0; j < WNF; j++) {
            bf16x8 bg = *(const bf16x8*)(&Bs[cur][(wn + j * 16 + fr) * 32 + fq * 8]);
#pragma unroll
            for (int i = 0; i < 4; i++)
                acc[i][j] = __builtin_amdgcn_mfma_f32_16x16x32_bf16(
                    af[i], bg, acc[i][j], 0, 0, 0);
        }

        // all waves done reading buf cur -> safe to overwrite with tile k+2.
        asm volatile("s_barrier" ::: "memory");
        // dummy tail reloads (tile 0) keep vmcnt bookkeeping uniform; they
        // target a buffer that is never read again.
        const int knext = (k + 2 < kIters) ? (k + 2) << 5 : 0;
        stage(cur, knext);
    }
#undef GLL
    asm volatile("s_waitcnt vmcnt(0)" ::: "memory");  // retire tail DMAs

    // epilogue: C/D layout col = lane&15 (n), row = (lane>>4)*4 + reg (m)
#pragma unroll
    for (int j = 0; j < WNF; j++) {
        int n = n0 + wn + j * 16 + fr;
        float bv = bias[n];
#pragma unroll
        for (int i = 0; i < 4; i++) {
#pragma unroll
            for (int r = 0; r < 4; r++) {
                int m = m0 + wm + i * 16 + fq * 4 + r;
                float v = acc[i][j][r] + bv;
                if (do_relu) v = fmaxf(v, 0.0f);
                if (resid16) v += bf2f(resid16[(size_t)m * N + n]);
                if (resid32) v += resid32[(size_t)m * N + n];
                C[(size_t)m * N + n] = f2bf(v);
            }
        }
    }
}

// -------- aggregation + final residual (in-place on d_out, f32) --------
// out[t=l*B+b][d] = emb32[t][d] + sum_m (bond[b,l,m]!=l) * msg[bond*B+b][d]
__global__ void agg_kernel(const float* __restrict__ emb32, const u16* __restrict__ msg,
                           const int* __restrict__ bond, float* __restrict__ out) {
    int t = blockIdx.x * 4 + (threadIdx.x >> 6);  // one wave per token
    int lane = threadIdx.x & 63;
    int l = t >> 7, b = t & 127;
    int d = lane * 8;
    float acc[8];
    {
        f32x8 v = *(const f32x8*)(emb32 + (size_t)t * DIM + d);
#pragma unroll
        for (int i = 0; i < 8; i++) acc[i] = v[i];
    }
    const int* bp = bond + ((size_t)b * NL + l) * 6;
#pragma unroll
    for (int m = 0; m < 6; m++) {
        int j = bp[m];
        if (j != l) {  // wave-uniform branch
            u16x8 g = *(const u16x8*)(msg + ((size_t)j * NB + b) * DIM + d);
#pragma unroll
            for (int i = 0; i < 8; i++) acc[i] += bf2f(g[i]);
        }
    }
    f32x8 o;
#pragma unroll
    for (int i = 0; i < 8; i++) o[i] = acc[i];
    *(f32x8*)(out + (size_t)t * DIM + d) = o;
}

extern "C" void kernel_launch(void* const* d_in, const int* in_sizes, int n_in,
                              void* d_out, int out_size, void* d_ws, size_t ws_size,
                              hipStream_t stream) {
    const int* element = (const int*)d_in[0];
    const int* bond    = (const int*)d_in[1];
    const int* aroma   = (const int*)d_in[2];
    const int* charge  = (const int*)d_in[3];
    const int* segment = (const int*)d_in[4];
    const float* pe      = (const float*)d_in[5];
    const float* E_elem  = (const float*)d_in[6];
    const float* E_charge= (const float*)d_in[7];
    const float* E_aroma = (const float*)d_in[8];
    const float* E_seg   = (const float*)d_in[9];
    const float* W1 = (const float*)d_in[10];
    const float* b1 = (const float*)d_in[11];
    const float* W2 = (const float*)d_in[12];
    const float* b2 = (const float*)d_in[13];
    const float* W3 = (const float*)d_in[14];
    const float* b3 = (const float*)d_in[15];
    const float* W4 = (const float*)d_in[16];
    const float* b4 = (const float*)d_in[17];
    const float* W5 = (const float*)d_in[18];
    const float* b5 = (const float*)d_in[19];

    // f32 emb lives in d_out (50 MiB); agg rewrites d_out in place at the end.
    float* emb32 = (float*)d_out;

    // dynamic ws layout — never exceed ws_size
    char* ws = (char*)d_ws;
    size_t woff = 0;
    auto take = [&](size_t bytes) -> u16* {
        u16* p = (u16*)(ws + woff);
        woff += (bytes + 255) & ~(size_t)255;
        return p;
    };
    u16* W1T = take((size_t)HID * DIM * 2);   // 2048x512 bf16
    u16* W2T = take((size_t)DIM * HID * 2);   // 512x2048
    u16* W3T = take((size_t)HID * DIM * 2);
    u16* W4T = take((size_t)DIM * HID * 2);
    u16* W5T = take((size_t)DIM * DIM * 2);
    u16* emb16 = take((size_t)NTOK * DIM * 2);  // 24 MiB
    u16* msg   = take((size_t)NTOK * DIM * 2);  // 24 MiB

    // pick largest M-chunk that fits (CM multiple of 128): h + xa + xb, bf16
    static const int ncs[] = {1, 2, 3, 4, 6, 8, 12, 16, 24, 32, 48, 64, 96, 192};
    int CM = 128;
    for (int nc : ncs) {
        int cm = NTOK / nc;
        if (cm % 128) continue;
        size_t need = woff + ((size_t)cm * HID * 2 + 256)
                           + ((size_t)cm * DIM * 2 + 256) * 2;
        if (need <= ws_size) { CM = cm; break; }
    }
    u16* hC  = take((size_t)CM * HID * 2);
    u16* xaC = take((size_t)CM * DIM * 2);
    u16* xbC = take((size_t)CM * DIM * 2);

    // weight transposes + cast: f32 (K,N) -> bf16 (N,K)
    transpose_f2b<<<dim3(HID / 32, DIM / 32), 256, 0, stream>>>(W1, W1T, DIM, HID);
    transpose_f2b<<<dim3(DIM / 32, HID / 32), 256, 0, stream>>>(W2, W2T, HID, DIM);
    transpose_f2b<<<dim3(HID / 32, DIM / 32), 256, 0, stream>>>(W3, W3T, DIM, HID);
    transpose_f2b<<<dim3(DIM / 32, HID / 32), 256, 0, stream>>>(W4, W4T, HID, DIM);
    transpose_f2b<<<dim3(DIM / 32, DIM / 32), 256, 0, stream>>>(W5, W5T, DIM, DIM);

    embed_kernel<<<NTOK / 4, 256, 0, stream>>>(element, aroma, charge, segment, pe,
                                               E_elem, E_charge, E_aroma, E_seg,
                                               emb32, emb16);

    // MLP per M-chunk: x += relu(x@W1+b1)@W2+b2 ; x += relu(x@W3+b3)@W4+b4 ; msg = x@W5+b5
    for (int c0 = 0; c0 < NTOK; c0 += CM) {
        const u16* x16 = emb16 + (size_t)c0 * DIM;
        const float* x32 = emb32 + (size_t)c0 * DIM;
        u16* msgC = msg + (size_t)c0 * DIM;
        gemm_bt<8><<<dim3(HID / 256, CM / 128), 256, 0, stream>>>(x16, W1T, b1, nullptr, nullptr, hC,  CM, HID, DIM, 1);
        gemm_bt<4><<<dim3(DIM / 128, CM / 128), 256, 0, stream>>>(hC,  W2T, b2, nullptr, x32,     xaC, CM, DIM, HID, 0);
        gemm_bt<8><<<dim3(HID / 256, CM / 128), 256, 0, stream>>>(xaC, W3T, b3, nullptr, nullptr, hC,  CM, HID, DIM, 1);
        gemm_bt<4><<<dim3(DIM / 128, CM / 128), 256, 0, stream>>>(hC,  W4T, b4, xaC,    nullptr,  xbC, CM, DIM, HID, 0);
        gemm_bt<4><<<dim3(DIM / 128, CM / 128), 256, 0, stream>>>(xbC, W5T, b5, nullptr, nullptr, msgC, CM, DIM, DIM, 0);
    }

    agg_kernel<<<NTOK / 4, 256, 0, stream>>>(emb32, msg, bond, (float*)d_out);
}